// Round 6
// baseline (118.928 us; speedup 1.0000x reference)
//
#include <hip/hip_runtime.h>
#include <hip/hip_bf16.h>
#include <math.h>

typedef __attribute__((ext_vector_type(8))) short      bf16x8;
typedef __attribute__((ext_vector_type(8))) unsigned short u16x8;
typedef __attribute__((ext_vector_type(4))) unsigned short u16x4;
typedef __attribute__((ext_vector_type(4))) float       f32x4;

#define BB 8
#define CC 64
#define HH 128
#define WW 128
#define EE 16
#define DTXT 512
#define HWSZ 16384
#define WCHUNKS 4608      // per pair: 2half * 9k * 4slot * 64co 16B chunks
#define WHALF 2304        // one 32-ci half
// conv1 geometry: 16x32 tile, halo 18x34, ci-half staged (4 chunks/px)
#define C1HR 18
#define C1HC 34
#define C1PX (C1HR * C1HC)      // 612
#define C1XCH (C1PX * 4)        // 2448 16B chunks (one ci-half)
// conv2 geometry: 16x16 tile, halo 18x18, full ci (8 chunks/px)
#define HLO 18
#define HPX2 324
#define XCH (HPX2 * 8)          // 2592

static __device__ __forceinline__ unsigned short f2bf(float f) {
  unsigned u = __float_as_uint(f);
  unsigned r = (u + 0x7FFFu + ((u >> 16) & 1u)) >> 16;  // RNE
  return (unsigned short)r;
}
static __device__ __forceinline__ float bf2f(unsigned short s) {
  return __uint_as_float(((unsigned)s) << 16);
}

// ---------------------------------------------------------------- xtprep (+pool partials)
__global__ __launch_bounds__(256) void xtprep_kernel(const float* __restrict__ x,
                                                     unsigned short* __restrict__ xT,
                                                     float* __restrict__ pp) {
  __shared__ unsigned short lt[256 * 70];
  __shared__ float red[256];
  const int b = blockIdx.y, p0 = blockIdx.x * 256;
  const int t = threadIdx.x;
  const float* xb = x + (size_t)b * CC * HWSZ + p0;
#pragma unroll 8
  for (int ci = 0; ci < CC; ++ci)
    lt[t * 70 + ci] = f2bf(xb[(size_t)ci * HWSZ + t]);
  __syncthreads();
  unsigned short* dstb = xT + ((size_t)b * HWSZ + p0) * CC;
#pragma unroll
  for (int it = 0; it < 8; ++it) {
    const int j = it * 256 + t;
    const int px = j >> 3, s = j & 7;
    u16x8 v;
#pragma unroll
    for (int i = 0; i < 8; ++i) v[i] = lt[px * 70 + s * 8 + i];
    *(u16x8*)(dstb + (size_t)j * 8) = v;
  }
  const int ci = t & 63, q = t >> 6;
  float s = 0.f;
#pragma unroll 16
  for (int px = q * 64; px < q * 64 + 64; ++px) s += bf2f(lt[px * 70 + ci]);
  red[t] = s;
  __syncthreads();
  if (t < 64)
    pp[((size_t)b * 64 + blockIdx.x) * 64 + t] =
        red[t] + red[t + 64] + red[t + 128] + red[t + 192];
}

// ---------------------------------------------------------------- gate
__global__ __launch_bounds__(256) void gate_kernel(const float* __restrict__ pp,
                                                   const float* __restrict__ text,
                                                   const float* __restrict__ Wx,
                                                   const float* __restrict__ Wt,
                                                   int* __restrict__ eidx,
                                                   float* __restrict__ gval,
                                                   float* __restrict__ aux_out) {
  __shared__ float pl[BB][CC];
  __shared__ float tx[BB * DTXT];
  __shared__ float wtl[DTXT * EE];
  __shared__ float logits[BB][EE];
  __shared__ float gates[BB][EE];
  __shared__ float imp[EE];
  const int t = threadIdx.x;

#pragma unroll
  for (int i = 0; i < BB * DTXT / 4 / 256; ++i)
    ((float4*)tx)[i * 256 + t] = ((const float4*)text)[i * 256 + t];
#pragma unroll
  for (int i = 0; i < DTXT * EE / 4 / 256; ++i)
    ((float4*)wtl)[i * 256 + t] = ((const float4*)Wt)[i * 256 + t];

#pragma unroll
  for (int jj = 0; jj < 2; ++jj) {
    const int j = jj * 256 + t;
    const int b = j >> 6, ci = j & 63;
    float s = 0.f;
#pragma unroll 8
    for (int blk = 0; blk < 64; ++blk) s += pp[((size_t)b * 64 + blk) * 64 + ci];
    pl[b][ci] = s * (1.f / (float)HWSZ);
  }
  __syncthreads();

  if (t < BB * EE) {
    const int b = t >> 4, e = t & 15;
    float s = 0.f;
#pragma unroll 8
    for (int c = 0; c < CC; ++c) s += pl[b][c] * Wx[c * EE + e];
#pragma unroll 8
    for (int d = 0; d < DTXT; ++d) s += tx[b * DTXT + d] * wtl[d * EE + e];
    logits[b][e] = s;
    gates[b][e] = 0.f;
  }
  __syncthreads();
  if (t < BB) {
    const int b = t;
    float v0 = -1e30f; int i0 = 0;
    for (int e = 0; e < EE; ++e) {
      float v = logits[b][e];
      if (v > v0) { v0 = v; i0 = e; }
    }
    float v1 = -1e30f; int i1 = 0;
    for (int e = 0; e < EE; ++e) {
      if (e == i0) continue;
      float v = logits[b][e];
      if (v > v1) { v1 = v; i1 = e; }
    }
    const float ex = expf(v1 - v0);
    const float g0 = 1.f / (1.f + ex);
    const float g1 = ex / (1.f + ex);
    gates[b][i0] = g0;
    gates[b][i1] = g1;
    eidx[2 * b] = i0;      gval[2 * b] = g0;
    eidx[2 * b + 1] = i1;  gval[2 * b + 1] = g1;
  }
  __syncthreads();
  if (t < EE) {
    float s = 0.f;
    for (int b = 0; b < BB; ++b) s += gates[b][t];
    imp[t] = s;
  }
  __syncthreads();
  if (t == 0) {
    float m = 0.f;
    for (int e = 0; e < EE; ++e) m += imp[e];
    m *= (1.f / EE);
    float v = 0.f;
    for (int e = 0; e < EE; ++e) { float d = imp[e] - m; v += d * d; }
    v *= (1.f / EE);
    aux_out[0] = v / (m * m + 1e-10f);
  }
}

// ---------------------------------------------------------------- wprep
__global__ __launch_bounds__(256) void wprep_kernel(const float* __restrict__ w1,
                                                    const float* __restrict__ w2,
                                                    const int* __restrict__ eidx,
                                                    const float* __restrict__ gval,
                                                    unsigned short* __restrict__ wp1,
                                                    unsigned short* __restrict__ wp2) {
  const int p = blockIdx.x;
  const int conv = blockIdx.y;
  const int e = eidx[p];
  const float g = conv ? gval[p] : 1.0f;
  const float* wsrc = (conv ? w2 : w1) + (size_t)e * CC * CC * 9;
  unsigned short* dst = (conv ? wp2 : wp1) + (size_t)p * WCHUNKS * 8;
  for (int c16 = threadIdx.x; c16 < WCHUNKS; c16 += 256) {
    const int co = c16 & 63;
    const int rest = c16 >> 6;
    const int s = rest & 3;
    const int ck = rest >> 2;
    const int k = ck % 9, half = ck / 9;
    const int ci0 = half * 32 + s * 8;
    u16x8 v;
#pragma unroll
    for (int i = 0; i < 8; ++i)
      v[i] = f2bf(g * wsrc[((size_t)co * CC + ci0 + i) * 9 + k]);
    *(u16x8*)(dst + (size_t)c16 * 8) = v;
  }
}

// ---------------------------------------------------------------- conv1 (16x32 tile)
// grid (32 tiles, 16 pairs), 512 thr, LDS 75.1 KB -> 2 blocks/CU.
__global__ __launch_bounds__(512, 4) void conv1_kernel(const u16x8* __restrict__ xT,
                                                       const u16x8* __restrict__ wp1,
                                                       const float* __restrict__ b1,
                                                       const int* __restrict__ eidx,
                                                       unsigned short* __restrict__ h) {
  __shared__ u16x8 xt[C1XCH];   // 39168 B, one ci-half, linear layout
  __shared__ u16x8 wt[WHALF];   // 36864 B
  const int t = threadIdx.x, lane = t & 63, w = t >> 6;
  const int tile = blockIdx.x, p = blockIdx.y;
  const int b = p >> 1, e = eidx[p];
  const int ty0 = (tile >> 2) * 16, tx0 = (tile & 3) * 32;
  const int ks = lane >> 4, ln = lane & 15;
  const u16x8* srcb = xT + (size_t)b * HWSZ * 8;
  const u16x8* wsrc = wp1 + (size_t)p * WCHUNKS;

  f32x4 acc[2][2][4];
#pragma unroll
  for (int i = 0; i < 2; ++i)
#pragma unroll
    for (int j = 0; j < 2; ++j)
#pragma unroll
      for (int k = 0; k < 4; ++k) acc[i][j][k] = (f32x4){0.f, 0.f, 0.f, 0.f};

#pragma unroll
  for (int half = 0; half < 2; ++half) {
    if (half) __syncthreads();  // protect xt/wt overwrite
    // stage xt ci-half: linear dest (B-frag reads are 1KB-contiguous -> conflict-free)
#pragma unroll
    for (int i = 0; i < 5; ++i) {
      const int idx = i * 512 + t;
      if (idx < C1XCH) {
        const int ph = idx >> 2, s = idx & 3;
        const int yy = ph / C1HC, xx = ph - yy * C1HC;
        const int gy = ty0 - 1 + yy, gx = tx0 - 1 + xx;
        u16x8 v = (u16x8){0, 0, 0, 0, 0, 0, 0, 0};
        if ((unsigned)gy < (unsigned)HH && (unsigned)gx < (unsigned)WW)
          v = srcb[(gy * WW + gx) * 8 + half * 4 + s];
        xt[ph * 4 + s] = v;
      }
    }
    // stage wt half
#pragma unroll
    for (int i = 0; i < 5; ++i) {
      const int idx = i * 512 + t;
      if (idx < WHALF) wt[idx] = wsrc[half * WHALF + idx];
    }
    __syncthreads();
    // compute
#pragma unroll
    for (int kk = 0; kk < 9; ++kk) {
      const int dy = kk / 3, dx = kk % 3;
      bf16x8 a[4];
#pragma unroll
      for (int mf = 0; mf < 4; ++mf)
        a[mf] = __builtin_bit_cast(bf16x8, wt[(kk * 4 + ks) * 64 + mf * 16 + ln]);
#pragma unroll
      for (int nfr = 0; nfr < 2; ++nfr)
#pragma unroll
        for (int nfc = 0; nfc < 2; ++nfc) {
          const int row = 2 * w + nfr + dy;
          const int col = nfc * 16 + ln + dx;
          const bf16x8 bfr = __builtin_bit_cast(bf16x8, xt[(row * C1HC + col) * 4 + ks]);
#pragma unroll
          for (int mf = 0; mf < 4; ++mf)
            acc[nfr][nfc][mf] = __builtin_amdgcn_mfma_f32_16x16x32_bf16(
                a[mf], bfr, acc[nfr][nfc][mf], 0, 0, 0);
        }
    }
  }

  // epilogue: bias + exact GELU via two 32KB LDS bounce passes (col halves)
  unsigned short* lt = (unsigned short*)xt;
  const int co_s = ks * 4;
  const int so = co_s >> 3;          // s contribution from ks
  const int off = co_s & 7;
#pragma unroll
  for (int c = 0; c < 2; ++c) {
    __syncthreads();   // pass0: xt readers done; pass1: copyout pass0 done
#pragma unroll
    for (int mf = 0; mf < 4; ++mf) {
      const float4 bv = *(const float4*)(b1 + e * CC + mf * 16 + co_s);
      const int s = mf * 2 + so;
#pragma unroll
      for (int nfr = 0; nfr < 2; ++nfr) {
        const int pxl = (2 * w + nfr) * 16 + ln;
        f32x4 v = acc[nfr][c][mf];
        float r0 = v.x + bv.x, r1 = v.y + bv.y, r2 = v.z + bv.z, r3 = v.w + bv.w;
        r0 = 0.5f * r0 * (1.f + erff(r0 * 0.70710678118654752f));
        r1 = 0.5f * r1 * (1.f + erff(r1 * 0.70710678118654752f));
        r2 = 0.5f * r2 * (1.f + erff(r2 * 0.70710678118654752f));
        r3 = 0.5f * r3 * (1.f + erff(r3 * 0.70710678118654752f));
        u16x4 pk = {f2bf(r0), f2bf(r1), f2bf(r2), f2bf(r3)};
        *(u16x4*)(lt + (pxl * 8 + (s ^ (pxl & 7))) * 8 + off) = pk;
      }
    }
    __syncthreads();
#pragma unroll
    for (int it = 0; it < 4; ++it) {
      const int j = it * 512 + t;
      const int px = j >> 3, s = j & 7;
      const u16x8 v = xt[px * 8 + (s ^ (px & 7))];
      const int gpx = (ty0 + (px >> 4)) * WW + tx0 + c * 16 + (px & 15);
      *(u16x8*)(h + ((size_t)p * HWSZ + gpx) * CC + s * 8) = v;
    }
  }
}

// ------------------------------------------------- conv2 helpers (R5 geometry)
static __device__ __forceinline__ void stage_xt2(const u16x8* __restrict__ src,
                                                 u16x8* xt, int ty0, int tx0, int t) {
#pragma unroll
  for (int i = 0; i < 6; ++i) {
    const int idx = i * 512 + t;
    if (idx < XCH) {
      const int ph = idx >> 3, s = idx & 7;
      const int yy = ph / HLO, xx = ph - yy * HLO;
      const int gy = ty0 - 1 + yy, gx = tx0 - 1 + xx;
      u16x8 v = (u16x8){0, 0, 0, 0, 0, 0, 0, 0};
      if ((unsigned)gy < (unsigned)HH && (unsigned)gx < (unsigned)WW)
        v = src[(gy * WW + gx) * 8 + s];
      xt[ph * 8 + (s ^ (ph & 7))] = v;
    }
  }
}

static __device__ __forceinline__ void half_body2(const u16x8* xt, const u16x8* wt,
                                                  int half, int lane, int w,
                                                  f32x4 acc[2][4]) {
  const int ks = lane >> 4, ln = lane & 15;
#pragma unroll
  for (int kk = 0; kk < 9; ++kk) {
    const int dy = kk / 3, dx = kk % 3;
    bf16x8 a[4];
#pragma unroll
    for (int mf = 0; mf < 4; ++mf)
      a[mf] = __builtin_bit_cast(bf16x8, wt[(kk * 4 + ks) * 64 + mf * 16 + ln]);
#pragma unroll
    for (int nfr = 0; nfr < 2; ++nfr) {
      const int row = 2 * w + nfr + dy;
      const int col = ln + dx;
      const int ph = row * HLO + col;
      const bf16x8 bfr = __builtin_bit_cast(bf16x8,
                xt[ph * 8 + ((half * 4 + ks) ^ (ph & 7))]);
#pragma unroll
      for (int mf = 0; mf < 4; ++mf)
        acc[nfr][mf] = __builtin_amdgcn_mfma_f32_16x16x32_bf16(a[mf], bfr,
                                                               acc[nfr][mf], 0, 0, 0);
    }
  }
}

// ---------------------------------------------------------------- conv2
// grid (64 tiles 16x16, 8 batch), 512 thr, 2 blocks/CU. Loops both slots.
// wt half1 prefetched to registers during half0 compute (T14).
__global__ __launch_bounds__(512, 4) void conv2_kernel(const u16x8* __restrict__ h,
                                                       const u16x8* __restrict__ wp2,
                                                       const float* __restrict__ b2,
                                                       const int* __restrict__ eidx,
                                                       const float* __restrict__ gval,
                                                       float* __restrict__ out) {
  __shared__ u16x8 xt[XCH];
  __shared__ u16x8 wt[WHALF];
  const int t = threadIdx.x, lane = t & 63, w = t >> 6;
  const int tile = blockIdx.x, b = blockIdx.y;
  const int ty0 = (tile >> 3) * 16, tx0 = (tile & 7) * 16;

  f32x4 acc[2][4];
#pragma unroll
  for (int i = 0; i < 2; ++i)
#pragma unroll
    for (int j = 0; j < 4; ++j) acc[i][j] = (f32x4){0.f, 0.f, 0.f, 0.f};

#pragma unroll
  for (int slot = 0; slot < 2; ++slot) {
    const int p = 2 * b + slot;
    const u16x8* wsrc = wp2 + (size_t)p * WCHUNKS;
    if (slot) __syncthreads();
    stage_xt2(h + (size_t)p * HWSZ * 8, xt, ty0, tx0, t);
#pragma unroll
    for (int i = 0; i < 5; ++i) {
      const int idx = i * 512 + t;
      if (idx < WHALF) wt[idx] = wsrc[idx];
    }
    __syncthreads();
    // prefetch half1 weights into registers (hidden under half0 compute)
    u16x8 pw[5];
#pragma unroll
    for (int i = 0; i < 5; ++i) {
      const int idx = i * 512 + t;
      if (idx < WHALF) pw[i] = wsrc[WHALF + idx];
    }
    half_body2(xt, wt, 0, lane, w, acc);
    __syncthreads();
#pragma unroll
    for (int i = 0; i < 5; ++i) {
      const int idx = i * 512 + t;
      if (idx < WHALF) wt[idx] = pw[i];
    }
    __syncthreads();
    half_body2(xt, wt, 1, lane, w, acc);
  }

  const int e0 = eidx[2 * b], e1 = eidx[2 * b + 1];
  const float g0 = gval[2 * b], g1 = gval[2 * b + 1];
  const int co_s = (lane >> 4) * 4;
  const int ln = lane & 15;
#pragma unroll
  for (int mf = 0; mf < 4; ++mf) {
    const float4 ba = *(const float4*)(b2 + e0 * CC + mf * 16 + co_s);
    const float4 bb = *(const float4*)(b2 + e1 * CC + mf * 16 + co_s);
    const float bx = g0 * ba.x + g1 * bb.x;
    const float by = g0 * ba.y + g1 * bb.y;
    const float bz = g0 * ba.z + g1 * bb.z;
    const float bw = g0 * ba.w + g1 * bb.w;
#pragma unroll
    for (int nfr = 0; nfr < 2; ++nfr) {
      const int row = 2 * w + nfr;
      const int gpx = (ty0 + row) * WW + tx0 + ln;
      f32x4 v = acc[nfr][mf];
      float* ob = out + (size_t)(b * CC + mf * 16 + co_s) * HWSZ + gpx;
      ob[0 * HWSZ] = v.x + bx;
      ob[1 * HWSZ] = v.y + by;
      ob[2 * HWSZ] = v.z + bz;
      ob[3 * HWSZ] = v.w + bw;
    }
  }
}

// ---------------------------------------------------------------- launch
extern "C" void kernel_launch(void* const* d_in, const int* in_sizes, int n_in,
                              void* d_out, int out_size, void* d_ws, size_t ws_size,
                              hipStream_t stream) {
  const float* x   = (const float*)d_in[0];
  const float* txt = (const float*)d_in[1];
  const float* Wx  = (const float*)d_in[2];
  const float* Wt  = (const float*)d_in[3];
  const float* w1  = (const float*)d_in[4];
  const float* b1  = (const float*)d_in[5];
  const float* w2  = (const float*)d_in[6];
  const float* b2  = (const float*)d_in[7];
  float* out = (float*)d_out;

  char* ws = (char*)d_ws;
  float* pp   = (float*)ws;                                  // 131,072 B
  int*   eidx = (int*)(ws + 131072);                         // 64 B
  float* gval = (float*)(ws + 131136);                       // 64 B
  unsigned short* wp1 = (unsigned short*)(ws + 132096);      // 1,179,648 B
  unsigned short* wp2 = (unsigned short*)(ws + 1311744);     // 1,179,648 B
  unsigned short* xT  = (unsigned short*)(ws + 2491392);     // 16,777,216 B
  unsigned short* h   = (unsigned short*)(ws + 19268608);    // 33,554,432 B

  xtprep_kernel<<<dim3(64, 8), 256, 0, stream>>>(x, xT, pp);
  gate_kernel<<<1, 256, 0, stream>>>(pp, txt, Wx, Wt, eidx, gval,
                                     out + (out_size - 1));
  wprep_kernel<<<dim3(16, 2), 256, 0, stream>>>(w1, w2, eidx, gval, wp1, wp2);
  conv1_kernel<<<dim3(32, 16), 512, 0, stream>>>((const u16x8*)xT, (const u16x8*)wp1,
                                                 b1, eidx, (unsigned short*)h);
  conv2_kernel<<<dim3(64, 8), 512, 0, stream>>>((const u16x8*)h, (const u16x8*)wp2,
                                                b2, eidx, gval, out);
}

// Round 7
// 111.984 us; speedup vs baseline: 1.0620x; 1.0620x over previous
//
#include <hip/hip_runtime.h>
#include <hip/hip_bf16.h>
#include <math.h>

typedef __attribute__((ext_vector_type(8))) short      bf16x8;
typedef __attribute__((ext_vector_type(8))) unsigned short u16x8;
typedef __attribute__((ext_vector_type(4))) unsigned short u16x4;
typedef __attribute__((ext_vector_type(4))) float       f32x4;

#define BB 8
#define CC 64
#define HH 128
#define WW 128
#define EE 16
#define DTXT 512
#define HWSZ 16384
#define WCHUNKS 4608      // per pair: 2half * 9k * 4slot * 64co 16B chunks
#define WHALF 2304        // one 32-ci half
#define HLO 18            // 16x16 tile + halo
#define HPX2 324
#define XCH (HPX2 * 8)    // 2592 16B chunks

static __device__ __forceinline__ unsigned short f2bf(float f) {
  unsigned u = __float_as_uint(f);
  unsigned r = (u + 0x7FFFu + ((u >> 16) & 1u)) >> 16;  // RNE
  return (unsigned short)r;
}
static __device__ __forceinline__ float bf2f(unsigned short s) {
  return __uint_as_float(((unsigned)s) << 16);
}

// ---------------------------------------------------------------- xtprep (+pool partials)
__global__ __launch_bounds__(256) void xtprep_kernel(const float* __restrict__ x,
                                                     unsigned short* __restrict__ xT,
                                                     float* __restrict__ pp) {
  __shared__ unsigned short lt[256 * 70];
  __shared__ float red[256];
  const int b = blockIdx.y, p0 = blockIdx.x * 256;
  const int t = threadIdx.x;
  const float* xb = x + (size_t)b * CC * HWSZ + p0;
#pragma unroll 8
  for (int ci = 0; ci < CC; ++ci)
    lt[t * 70 + ci] = f2bf(xb[(size_t)ci * HWSZ + t]);
  __syncthreads();
  unsigned short* dstb = xT + ((size_t)b * HWSZ + p0) * CC;
#pragma unroll
  for (int it = 0; it < 8; ++it) {
    const int j = it * 256 + t;
    const int px = j >> 3, s = j & 7;
    u16x8 v;
#pragma unroll
    for (int i = 0; i < 8; ++i) v[i] = lt[px * 70 + s * 8 + i];
    *(u16x8*)(dstb + (size_t)j * 8) = v;
  }
  const int ci = t & 63, q = t >> 6;
  float s = 0.f;
#pragma unroll 16
  for (int px = q * 64; px < q * 64 + 64; ++px) s += bf2f(lt[px * 70 + ci]);
  red[t] = s;
  __syncthreads();
  if (t < 64)
    pp[((size_t)b * 64 + blockIdx.x) * 64 + t] =
        red[t] + red[t + 64] + red[t + 128] + red[t + 192];
}

// ---------------------------------------------------------------- gwprep
// Each of 32 blocks redundantly computes the gate (deterministic, identical),
// then emits its weight slice + gathered biases. Block (0,0) writes aux loss.
__global__ __launch_bounds__(256) void gwprep_kernel(const float* __restrict__ pp,
                                                     const float* __restrict__ text,
                                                     const float* __restrict__ Wx,
                                                     const float* __restrict__ Wt,
                                                     const float* __restrict__ w1,
                                                     const float* __restrict__ w2,
                                                     const float* __restrict__ b1,
                                                     const float* __restrict__ b2,
                                                     unsigned short* __restrict__ wp1,
                                                     unsigned short* __restrict__ wp2,
                                                     float* __restrict__ bg1,
                                                     float* __restrict__ bg2p,
                                                     float* __restrict__ aux_out) {
  __shared__ float pl[BB][CC];
  __shared__ float tx[BB * DTXT];
  __shared__ float wtl[DTXT * EE];
  __shared__ float logits[BB][EE];
  __shared__ float gates[BB][EE];
  __shared__ float imp[EE];
  __shared__ int   s_eidx[16];
  __shared__ float s_gval[16];
  const int t = threadIdx.x;

#pragma unroll
  for (int i = 0; i < BB * DTXT / 4 / 256; ++i)
    ((float4*)tx)[i * 256 + t] = ((const float4*)text)[i * 256 + t];
#pragma unroll
  for (int i = 0; i < DTXT * EE / 4 / 256; ++i)
    ((float4*)wtl)[i * 256 + t] = ((const float4*)Wt)[i * 256 + t];

#pragma unroll
  for (int jj = 0; jj < 2; ++jj) {
    const int j = jj * 256 + t;
    const int b = j >> 6, ci = j & 63;
    float s = 0.f;
#pragma unroll 8
    for (int blk = 0; blk < 64; ++blk) s += pp[((size_t)b * 64 + blk) * 64 + ci];
    pl[b][ci] = s * (1.f / (float)HWSZ);
  }
  __syncthreads();

  if (t < BB * EE) {
    const int b = t >> 4, e = t & 15;
    float s = 0.f;
#pragma unroll 8
    for (int c = 0; c < CC; ++c) s += pl[b][c] * Wx[c * EE + e];
#pragma unroll 8
    for (int d = 0; d < DTXT; ++d) s += tx[b * DTXT + d] * wtl[d * EE + e];
    logits[b][e] = s;
    gates[b][e] = 0.f;
  }
  __syncthreads();
  if (t < BB) {
    const int b = t;
    float v0 = -1e30f; int i0 = 0;
    for (int e = 0; e < EE; ++e) {
      float v = logits[b][e];
      if (v > v0) { v0 = v; i0 = e; }
    }
    float v1 = -1e30f; int i1 = 0;
    for (int e = 0; e < EE; ++e) {
      if (e == i0) continue;
      float v = logits[b][e];
      if (v > v1) { v1 = v; i1 = e; }
    }
    const float ex = expf(v1 - v0);
    const float g0 = 1.f / (1.f + ex);
    const float g1 = ex / (1.f + ex);
    gates[b][i0] = g0;
    gates[b][i1] = g1;
    s_eidx[2 * b] = i0;      s_gval[2 * b] = g0;
    s_eidx[2 * b + 1] = i1;  s_gval[2 * b + 1] = g1;
  }
  __syncthreads();

  const int p = blockIdx.x;
  const int conv = blockIdx.y;
  const int e = s_eidx[p];
  const float g = conv ? s_gval[p] : 1.0f;

  // gathered biases
  if (t < CC) {
    if (conv == 0) bg1[p * CC + t] = b1[e * CC + t];
    else           bg2p[p * CC + t] = s_gval[p] * b2[e * CC + t];
  }
  // aux loss (block (0,0) only)
  if (p == 0 && conv == 0) {
    if (t < EE) {
      float s = 0.f;
      for (int b = 0; b < BB; ++b) s += gates[b][t];
      imp[t] = s;
    }
    __syncthreads();
    if (t == 0) {
      float m = 0.f;
      for (int ee = 0; ee < EE; ++ee) m += imp[ee];
      m *= (1.f / EE);
      float v = 0.f;
      for (int ee = 0; ee < EE; ++ee) { float d = imp[ee] - m; v += d * d; }
      v *= (1.f / EE);
      aux_out[0] = v / (m * m + 1e-10f);
    }
  }

  // weight slice: wp[pair][half2][k9][slot4][co64][8ci], gate folded for conv2
  const float* wsrc = (conv ? w2 : w1) + (size_t)e * CC * CC * 9;
  unsigned short* dst = (conv ? wp2 : wp1) + (size_t)p * WCHUNKS * 8;
  for (int c16 = t; c16 < WCHUNKS; c16 += 256) {
    const int co = c16 & 63;
    const int rest = c16 >> 6;
    const int s = rest & 3;
    const int ck = rest >> 2;
    const int k = ck % 9, half = ck / 9;
    const int ci0 = half * 32 + s * 8;
    u16x8 v;
#pragma unroll
    for (int i = 0; i < 8; ++i)
      v[i] = f2bf(g * wsrc[((size_t)co * CC + ci0 + i) * 9 + k]);
    *(u16x8*)(dst + (size_t)c16 * 8) = v;
  }
}

// ------------------------------------------------- conv core helpers (R5-proven)
static __device__ __forceinline__ void stage_xt2(const u16x8* __restrict__ src,
                                                 u16x8* xt, int ty0, int tx0, int t) {
#pragma unroll
  for (int i = 0; i < 6; ++i) {
    const int idx = i * 512 + t;
    if (idx < XCH) {
      const int ph = idx >> 3, s = idx & 7;
      const int yy = ph / HLO, xx = ph - yy * HLO;
      const int gy = ty0 - 1 + yy, gx = tx0 - 1 + xx;
      u16x8 v = (u16x8){0, 0, 0, 0, 0, 0, 0, 0};
      if ((unsigned)gy < (unsigned)HH && (unsigned)gx < (unsigned)WW)
        v = src[(gy * WW + gx) * 8 + s];
      xt[ph * 8 + (s ^ (ph & 7))] = v;
    }
  }
}

static __device__ __forceinline__ void half_body2(const u16x8* xt, const u16x8* wt,
                                                  int half, int lane, int w,
                                                  f32x4 acc[2][4]) {
  const int ks = lane >> 4, ln = lane & 15;
#pragma unroll
  for (int kk = 0; kk < 9; ++kk) {
    const int dy = kk / 3, dx = kk % 3;
    bf16x8 a[4];
#pragma unroll
    for (int mf = 0; mf < 4; ++mf)
      a[mf] = __builtin_bit_cast(bf16x8, wt[(kk * 4 + ks) * 64 + mf * 16 + ln]);
#pragma unroll
    for (int nfr = 0; nfr < 2; ++nfr) {
      const int row = 2 * w + nfr + dy;
      const int col = ln + dx;
      const int ph = row * HLO + col;
      const bf16x8 bfr = __builtin_bit_cast(bf16x8,
                xt[ph * 8 + ((half * 4 + ks) ^ (ph & 7))]);
#pragma unroll
      for (int mf = 0; mf < 4; ++mf)
        acc[nfr][mf] = __builtin_amdgcn_mfma_f32_16x16x32_bf16(a[mf], bfr,
                                                               acc[nfr][mf], 0, 0, 0);
    }
  }
}

// ---------------------------------------------------------------- conv1
// grid (64 tiles 16x16, 8 b), 512 thr, 2 blocks/CU. xT tile staged ONCE, both slots computed.
__global__ __launch_bounds__(512, 4) void conv1_kernel(const u16x8* __restrict__ xT,
                                                       const u16x8* __restrict__ wp1,
                                                       const float* __restrict__ bg1,
                                                       unsigned short* __restrict__ h) {
  __shared__ u16x8 xt[XCH];     // 41472 B
  __shared__ u16x8 wt[WHALF];   // 36864 B -> 78336 B total, 2 blocks/CU
  const int t = threadIdx.x, lane = t & 63, w = t >> 6;
  const int tile = blockIdx.x, b = blockIdx.y;
  const int ty0 = (tile >> 3) * 16, tx0 = (tile & 7) * 16;

  f32x4 acc[2][2][4];   // [slot][nfr][mf]
#pragma unroll
  for (int s = 0; s < 2; ++s)
#pragma unroll
    for (int i = 0; i < 2; ++i)
#pragma unroll
      for (int j = 0; j < 4; ++j) acc[s][i][j] = (f32x4){0.f, 0.f, 0.f, 0.f};

  stage_xt2(xT + (size_t)b * HWSZ * 8, xt, ty0, tx0, t);

#pragma unroll
  for (int slot = 0; slot < 2; ++slot) {
    const u16x8* wsrc = wp1 + (size_t)(2 * b + slot) * WCHUNKS;
#pragma unroll
    for (int half = 0; half < 2; ++half) {
      if (slot | half) __syncthreads();   // wt readers done before overwrite
#pragma unroll
      for (int i = 0; i < 5; ++i) {
        const int idx = i * 512 + t;
        if (idx < WHALF) wt[idx] = wsrc[half * WHALF + idx];
      }
      __syncthreads();
      half_body2(xt, wt, half, lane, w, acc[slot]);
    }
  }

  // epilogue: both slots, bias + exact GELU via swizzled LDS bounce
  unsigned short* lt = (unsigned short*)xt;
  const int ks = lane >> 4, ln = lane & 15;
  const int co_s = ks * 4;
  const int so = co_s >> 3, off = co_s & 7;
#pragma unroll
  for (int slot = 0; slot < 2; ++slot) {
    const int p = 2 * b + slot;
    __syncthreads();   // xt/lt readers done
#pragma unroll
    for (int mf = 0; mf < 4; ++mf) {
      const float4 bv = *(const float4*)(bg1 + p * CC + mf * 16 + co_s);
      const int s = mf * 2 + so;
#pragma unroll
      for (int nfr = 0; nfr < 2; ++nfr) {
        const int pxl = (2 * w + nfr) * 16 + ln;
        f32x4 v = acc[slot][nfr][mf];
        float r0 = v.x + bv.x, r1 = v.y + bv.y, r2 = v.z + bv.z, r3 = v.w + bv.w;
        r0 = 0.5f * r0 * (1.f + erff(r0 * 0.70710678118654752f));
        r1 = 0.5f * r1 * (1.f + erff(r1 * 0.70710678118654752f));
        r2 = 0.5f * r2 * (1.f + erff(r2 * 0.70710678118654752f));
        r3 = 0.5f * r3 * (1.f + erff(r3 * 0.70710678118654752f));
        u16x4 pk = {f2bf(r0), f2bf(r1), f2bf(r2), f2bf(r3)};
        *(u16x4*)(lt + (pxl * 8 + (s ^ (pxl & 7))) * 8 + off) = pk;
      }
    }
    __syncthreads();
#pragma unroll
    for (int it = 0; it < 4; ++it) {
      const int j = it * 512 + t;
      const int px = j >> 3, s = j & 7;
      const u16x8 v = xt[px * 8 + (s ^ (px & 7))];
      const int gpx = (ty0 + (px >> 4)) * WW + tx0 + (px & 15);
      *(u16x8*)(h + ((size_t)p * HWSZ + gpx) * CC + s * 8) = v;
    }
  }
}

// ---------------------------------------------------------------- conv2
// grid (64 tiles 16x16, 8 b), 512 thr, 2 blocks/CU. Loops both slots; wt half1 reg-prefetch.
__global__ __launch_bounds__(512, 4) void conv2_kernel(const u16x8* __restrict__ h,
                                                       const u16x8* __restrict__ wp2,
                                                       const float* __restrict__ bg2p,
                                                       float* __restrict__ out) {
  __shared__ u16x8 xt[XCH];
  __shared__ u16x8 wt[WHALF];
  const int t = threadIdx.x, lane = t & 63, w = t >> 6;
  const int tile = blockIdx.x, b = blockIdx.y;
  const int ty0 = (tile >> 3) * 16, tx0 = (tile & 7) * 16;

  f32x4 acc[2][4];
#pragma unroll
  for (int i = 0; i < 2; ++i)
#pragma unroll
    for (int j = 0; j < 4; ++j) acc[i][j] = (f32x4){0.f, 0.f, 0.f, 0.f};

#pragma unroll
  for (int slot = 0; slot < 2; ++slot) {
    const int p = 2 * b + slot;
    const u16x8* wsrc = wp2 + (size_t)p * WCHUNKS;
    if (slot) __syncthreads();
    stage_xt2(h + (size_t)p * HWSZ * 8, xt, ty0, tx0, t);
#pragma unroll
    for (int i = 0; i < 5; ++i) {
      const int idx = i * 512 + t;
      if (idx < WHALF) wt[idx] = wsrc[idx];
    }
    __syncthreads();
    u16x8 pw[5];
#pragma unroll
    for (int i = 0; i < 5; ++i) {
      const int idx = i * 512 + t;
      if (idx < WHALF) pw[i] = wsrc[WHALF + idx];
    }
    half_body2(xt, wt, 0, lane, w, acc);
    __syncthreads();
#pragma unroll
    for (int i = 0; i < 5; ++i) {
      const int idx = i * 512 + t;
      if (idx < WHALF) wt[idx] = pw[i];
    }
    __syncthreads();
    half_body2(xt, wt, 1, lane, w, acc);
  }

  const int co_s = (lane >> 4) * 4;
  const int ln = lane & 15;
#pragma unroll
  for (int mf = 0; mf < 4; ++mf) {
    const float4 ba = *(const float4*)(bg2p + (2 * b) * CC + mf * 16 + co_s);
    const float4 bb = *(const float4*)(bg2p + (2 * b + 1) * CC + mf * 16 + co_s);
    const float bx = ba.x + bb.x;
    const float by = ba.y + bb.y;
    const float bz = ba.z + bb.z;
    const float bw = ba.w + bb.w;
#pragma unroll
    for (int nfr = 0; nfr < 2; ++nfr) {
      const int row = 2 * w + nfr;
      const int gpx = (ty0 + row) * WW + tx0 + ln;
      f32x4 v = acc[nfr][mf];
      float* ob = out + (size_t)(b * CC + mf * 16 + co_s) * HWSZ + gpx;
      ob[0 * HWSZ] = v.x + bx;
      ob[1 * HWSZ] = v.y + by;
      ob[2 * HWSZ] = v.z + bz;
      ob[3 * HWSZ] = v.w + bw;
    }
  }
}

// ---------------------------------------------------------------- launch
extern "C" void kernel_launch(void* const* d_in, const int* in_sizes, int n_in,
                              void* d_out, int out_size, void* d_ws, size_t ws_size,
                              hipStream_t stream) {
  const float* x   = (const float*)d_in[0];
  const float* txt = (const float*)d_in[1];
  const float* Wx  = (const float*)d_in[2];
  const float* Wt  = (const float*)d_in[3];
  const float* w1  = (const float*)d_in[4];
  const float* b1  = (const float*)d_in[5];
  const float* w2  = (const float*)d_in[6];
  const float* b2  = (const float*)d_in[7];
  float* out = (float*)d_out;

  char* ws = (char*)d_ws;
  float* pp   = (float*)ws;                                  // 131,072 B
  float* bg1  = (float*)(ws + 131072);                       // 4,096 B
  float* bg2p = (float*)(ws + 135168);                       // 4,096 B
  unsigned short* wp1 = (unsigned short*)(ws + 139264);      // 1,179,648 B
  unsigned short* wp2 = (unsigned short*)(ws + 1318912);     // 1,179,648 B
  unsigned short* xT  = (unsigned short*)(ws + 2498560);     // 16,777,216 B
  unsigned short* h   = (unsigned short*)(ws + 19275776);    // 33,554,432 B

  xtprep_kernel<<<dim3(64, 8), 256, 0, stream>>>(x, xT, pp);
  gwprep_kernel<<<dim3(16, 2), 256, 0, stream>>>(pp, txt, Wx, Wt, w1, w2, b1, b2,
                                                 wp1, wp2, bg1, bg2p,
                                                 out + (out_size - 1));
  conv1_kernel<<<dim3(64, 8), 512, 0, stream>>>((const u16x8*)xT, (const u16x8*)wp1,
                                                bg1, (unsigned short*)h);
  conv2_kernel<<<dim3(64, 8), 512, 0, stream>>>((const u16x8*)h, (const u16x8*)wp2,
                                                bg2p, out);
}

// Round 8
// 100.876 us; speedup vs baseline: 1.1790x; 1.1101x over previous
//
#include <hip/hip_runtime.h>
#include <hip/hip_bf16.h>
#include <math.h>

typedef __attribute__((ext_vector_type(8))) short      bf16x8;
typedef __attribute__((ext_vector_type(8))) unsigned short u16x8;
typedef __attribute__((ext_vector_type(4))) unsigned short u16x4;
typedef __attribute__((ext_vector_type(4))) float       f32x4;

#define BB 8
#define CC 64
#define HH 128
#define WW 128
#define EE 16
#define DTXT 512
#define HWSZ 16384
#define WCHUNKS 4608      // per pair: 2half * 9k * 4slot * 64co 16B chunks
#define WHALF 2304        // one 32-ci half
#define HLO 18            // 16x16 tile + halo
#define HPX2 324
#define XCH (HPX2 * 8)    // 2592 16B chunks

static __device__ __forceinline__ unsigned short f2bf(float f) {
  unsigned u = __float_as_uint(f);
  unsigned r = (u + 0x7FFFu + ((u >> 16) & 1u)) >> 16;  // RNE
  return (unsigned short)r;
}
static __device__ __forceinline__ float bf2f(unsigned short s) {
  return __uint_as_float(((unsigned)s) << 16);
}

// ---------------------------------------------------------------- xtprep (+pool partials)
__global__ __launch_bounds__(256) void xtprep_kernel(const float* __restrict__ x,
                                                     unsigned short* __restrict__ xT,
                                                     float* __restrict__ pp) {
  __shared__ unsigned short lt[256 * 70];
  __shared__ float red[256];
  const int b = blockIdx.y, p0 = blockIdx.x * 256;
  const int t = threadIdx.x;
  const float* xb = x + (size_t)b * CC * HWSZ + p0;
#pragma unroll 8
  for (int ci = 0; ci < CC; ++ci)
    lt[t * 70 + ci] = f2bf(xb[(size_t)ci * HWSZ + t]);
  __syncthreads();
  unsigned short* dstb = xT + ((size_t)b * HWSZ + p0) * CC;
#pragma unroll
  for (int it = 0; it < 8; ++it) {
    const int j = it * 256 + t;
    const int px = j >> 3, s = j & 7;
    u16x8 v;
#pragma unroll
    for (int i = 0; i < 8; ++i) v[i] = lt[px * 70 + s * 8 + i];
    *(u16x8*)(dstb + (size_t)j * 8) = v;
  }
  const int ci = t & 63, q = t >> 6;
  float s = 0.f;
#pragma unroll 16
  for (int px = q * 64; px < q * 64 + 64; ++px) s += bf2f(lt[px * 70 + ci]);
  red[t] = s;
  __syncthreads();
  if (t < 64)
    pp[((size_t)b * 64 + blockIdx.x) * 64 + t] =
        red[t] + red[t + 64] + red[t + 128] + red[t + 192];
}

// ---------------------------------------------------------------- gwprep
// grid (16 pairs, 2 convs, 4 slices). Every block redundantly computes the gate
// (deterministic, identical), then emits its quarter of the weight slice.
__global__ __launch_bounds__(256) void gwprep_kernel(const float* __restrict__ pp,
                                                     const float* __restrict__ text,
                                                     const float* __restrict__ Wx,
                                                     const float* __restrict__ Wt,
                                                     const float* __restrict__ w1,
                                                     const float* __restrict__ w2,
                                                     const float* __restrict__ b1,
                                                     const float* __restrict__ b2,
                                                     unsigned short* __restrict__ wp1,
                                                     unsigned short* __restrict__ wp2,
                                                     float* __restrict__ bg1,
                                                     float* __restrict__ bg2p,
                                                     float* __restrict__ aux_out) {
  __shared__ float pl[BB][CC];
  __shared__ float tx[BB * DTXT];
  __shared__ float wtl[DTXT * EE];
  __shared__ float logits[BB][EE];
  __shared__ float gates[BB][EE];
  __shared__ float imp[EE];
  __shared__ int   s_eidx[16];
  __shared__ float s_gval[16];
  const int t = threadIdx.x;

#pragma unroll
  for (int i = 0; i < BB * DTXT / 4 / 256; ++i)
    ((float4*)tx)[i * 256 + t] = ((const float4*)text)[i * 256 + t];
#pragma unroll
  for (int i = 0; i < DTXT * EE / 4 / 256; ++i)
    ((float4*)wtl)[i * 256 + t] = ((const float4*)Wt)[i * 256 + t];

#pragma unroll
  for (int jj = 0; jj < 2; ++jj) {
    const int j = jj * 256 + t;
    const int b = j >> 6, ci = j & 63;
    float s = 0.f;
#pragma unroll 8
    for (int blk = 0; blk < 64; ++blk) s += pp[((size_t)b * 64 + blk) * 64 + ci];
    pl[b][ci] = s * (1.f / (float)HWSZ);
  }
  __syncthreads();

  if (t < BB * EE) {
    const int b = t >> 4, e = t & 15;
    float s = 0.f;
#pragma unroll 8
    for (int c = 0; c < CC; ++c) s += pl[b][c] * Wx[c * EE + e];
#pragma unroll 8
    for (int d = 0; d < DTXT; ++d) s += tx[b * DTXT + d] * wtl[d * EE + e];
    logits[b][e] = s;
    gates[b][e] = 0.f;
  }
  __syncthreads();
  if (t < BB) {
    const int b = t;
    float v0 = -1e30f; int i0 = 0;
    for (int e = 0; e < EE; ++e) {
      float v = logits[b][e];
      if (v > v0) { v0 = v; i0 = e; }
    }
    float v1 = -1e30f; int i1 = 0;
    for (int e = 0; e < EE; ++e) {
      if (e == i0) continue;
      float v = logits[b][e];
      if (v > v1) { v1 = v; i1 = e; }
    }
    const float ex = expf(v1 - v0);
    const float g0 = 1.f / (1.f + ex);
    const float g1 = ex / (1.f + ex);
    gates[b][i0] = g0;
    gates[b][i1] = g1;
    s_eidx[2 * b] = i0;      s_gval[2 * b] = g0;
    s_eidx[2 * b + 1] = i1;  s_gval[2 * b + 1] = g1;
  }
  __syncthreads();

  const int p = blockIdx.x;
  const int conv = blockIdx.y;
  const int z = blockIdx.z;
  const int e = s_eidx[p];
  const float g = conv ? s_gval[p] : 1.0f;

  if (z == 0 && t < CC) {
    if (conv == 0) bg1[p * CC + t] = b1[e * CC + t];
    else           bg2p[p * CC + t] = s_gval[p] * b2[e * CC + t];
  }
  if (p == 0 && conv == 0 && z == 0) {
    if (t < EE) {
      float s = 0.f;
      for (int b = 0; b < BB; ++b) s += gates[b][t];
      imp[t] = s;
    }
    __syncthreads();
    if (t == 0) {
      float m = 0.f;
      for (int ee = 0; ee < EE; ++ee) m += imp[ee];
      m *= (1.f / EE);
      float v = 0.f;
      for (int ee = 0; ee < EE; ++ee) { float d = imp[ee] - m; v += d * d; }
      v *= (1.f / EE);
      aux_out[0] = v / (m * m + 1e-10f);
    }
  }

  // weight slice quarter: wp[pair][half2][k9][slot4][co64][8ci]
  const float* wsrc = (conv ? w2 : w1) + (size_t)e * CC * CC * 9;
  unsigned short* dst = (conv ? wp2 : wp1) + (size_t)p * WCHUNKS * 8;
  const int c16_end = (z + 1) * (WCHUNKS / 4);
  for (int c16 = z * (WCHUNKS / 4) + t; c16 < c16_end; c16 += 256) {
    const int co = c16 & 63;
    const int rest = c16 >> 6;
    const int s = rest & 3;
    const int ck = rest >> 2;
    const int k = ck % 9, half = ck / 9;
    const int ci0 = half * 32 + s * 8;
    u16x8 v;
#pragma unroll
    for (int i = 0; i < 8; ++i)
      v[i] = f2bf(g * wsrc[((size_t)co * CC + ci0 + i) * 9 + k]);
    *(u16x8*)(dst + (size_t)c16 * 8) = v;
  }
}

// ------------------------------------------------- conv core helpers
static __device__ __forceinline__ void stage_xt2(const u16x8* __restrict__ src,
                                                 u16x8* xt, int ty0, int tx0, int t) {
#pragma unroll
  for (int i = 0; i < 6; ++i) {
    const int idx = i * 512 + t;
    if (idx < XCH) {
      const int ph = idx >> 3, s = idx & 7;
      const int yy = ph / HLO, xx = ph - yy * HLO;
      const int gy = ty0 - 1 + yy, gx = tx0 - 1 + xx;
      u16x8 v = (u16x8){0, 0, 0, 0, 0, 0, 0, 0};
      if ((unsigned)gy < (unsigned)HH && (unsigned)gx < (unsigned)WW)
        v = src[(gy * WW + gx) * 8 + s];
      xt[ph * 8 + (s ^ (ph & 7))] = v;
    }
  }
}

static __device__ __forceinline__ void half_body2(const u16x8* xt, const u16x8* wt,
                                                  int half, int lane, int w,
                                                  f32x4 acc[2][4]) {
  const int ks = lane >> 4, ln = lane & 15;
#pragma unroll
  for (int kk = 0; kk < 9; ++kk) {
    const int dy = kk / 3, dx = kk % 3;
    bf16x8 a[4];
#pragma unroll
    for (int mf = 0; mf < 4; ++mf)
      a[mf] = __builtin_bit_cast(bf16x8, wt[(kk * 4 + ks) * 64 + mf * 16 + ln]);
#pragma unroll
    for (int nfr = 0; nfr < 2; ++nfr) {
      const int row = 2 * w + nfr + dy;
      const int col = ln + dx;
      const int ph = row * HLO + col;
      const bf16x8 bfr = __builtin_bit_cast(bf16x8,
                xt[ph * 8 + ((half * 4 + ks) ^ (ph & 7))]);
#pragma unroll
      for (int mf = 0; mf < 4; ++mf)
        acc[nfr][mf] = __builtin_amdgcn_mfma_f32_16x16x32_bf16(a[mf], bfr,
                                                               acc[nfr][mf], 0, 0, 0);
    }
  }
}

// ---------------------------------------------------------------- conv1
// grid (64 tiles 16x16, 8 b), 512 thr, 2 blocks/CU. xT staged once; 4 wt stages
// pipelined via single-reg-buffer prefetch (T14); setprio around MFMA (T5).
__global__ __launch_bounds__(512, 4) void conv1_kernel(const u16x8* __restrict__ xT,
                                                       const u16x8* __restrict__ wp1,
                                                       const float* __restrict__ bg1,
                                                       unsigned short* __restrict__ h) {
  __shared__ u16x8 xt[XCH];     // 41472 B
  __shared__ u16x8 wt[WHALF];   // 36864 B -> 78336 B total
  const int t = threadIdx.x, lane = t & 63, w = t >> 6;
  const int tile = blockIdx.x, b = blockIdx.y;
  const int ty0 = (tile >> 3) * 16, tx0 = (tile & 7) * 16;

  f32x4 acc[2][2][4];   // [slot][nfr][mf]
#pragma unroll
  for (int s = 0; s < 2; ++s)
#pragma unroll
    for (int i = 0; i < 2; ++i)
#pragma unroll
      for (int j = 0; j < 4; ++j) acc[s][i][j] = (f32x4){0.f, 0.f, 0.f, 0.f};

  stage_xt2(xT + (size_t)b * HWSZ * 8, xt, ty0, tx0, t);
  {
    const u16x8* w0 = wp1 + (size_t)(2 * b) * WCHUNKS;
#pragma unroll
    for (int i = 0; i < 5; ++i) {
      const int idx = i * 512 + t;
      if (idx < WHALF) wt[idx] = w0[idx];
    }
  }
  __syncthreads();

  u16x8 pw[5];
#pragma unroll
  for (int st = 0; st < 4; ++st) {
    const int slot = st >> 1, half = st & 1;
    if (st < 3) {  // issue next stage's global loads before compute
      const u16x8* nw = wp1 + (size_t)(2 * b + ((st + 1) >> 1)) * WCHUNKS
                        + ((st + 1) & 1) * WHALF;
#pragma unroll
      for (int i = 0; i < 5; ++i) {
        const int idx = i * 512 + t;
        if (idx < WHALF) pw[i] = nw[idx];
      }
    }
    __builtin_amdgcn_s_setprio(1);
    half_body2(xt, wt, half, lane, w, acc[slot]);
    __builtin_amdgcn_s_setprio(0);
    __syncthreads();
    if (st < 3) {
#pragma unroll
      for (int i = 0; i < 5; ++i) {
        const int idx = i * 512 + t;
        if (idx < WHALF) wt[idx] = pw[i];
      }
      __syncthreads();
    }
  }

  // epilogue: both slots, bias + exact GELU via swizzled LDS bounce
  unsigned short* lt = (unsigned short*)xt;
  const int ks = lane >> 4, ln = lane & 15;
  const int co_s = ks * 4;
  const int so = co_s >> 3, off = co_s & 7;
#pragma unroll
  for (int slot = 0; slot < 2; ++slot) {
    const int p = 2 * b + slot;
    __syncthreads();
#pragma unroll
    for (int mf = 0; mf < 4; ++mf) {
      const float4 bv = *(const float4*)(bg1 + p * CC + mf * 16 + co_s);
      const int s = mf * 2 + so;
#pragma unroll
      for (int nfr = 0; nfr < 2; ++nfr) {
        const int pxl = (2 * w + nfr) * 16 + ln;
        f32x4 v = acc[slot][nfr][mf];
        float r0 = v.x + bv.x, r1 = v.y + bv.y, r2 = v.z + bv.z, r3 = v.w + bv.w;
        r0 = 0.5f * r0 * (1.f + erff(r0 * 0.70710678118654752f));
        r1 = 0.5f * r1 * (1.f + erff(r1 * 0.70710678118654752f));
        r2 = 0.5f * r2 * (1.f + erff(r2 * 0.70710678118654752f));
        r3 = 0.5f * r3 * (1.f + erff(r3 * 0.70710678118654752f));
        u16x4 pk = {f2bf(r0), f2bf(r1), f2bf(r2), f2bf(r3)};
        *(u16x4*)(lt + (pxl * 8 + (s ^ (pxl & 7))) * 8 + off) = pk;
      }
    }
    __syncthreads();
#pragma unroll
    for (int it = 0; it < 4; ++it) {
      const int j = it * 512 + t;
      const int px = j >> 3, s = j & 7;
      const u16x8 v = xt[px * 8 + (s ^ (px & 7))];
      const int gpx = (ty0 + (px >> 4)) * WW + tx0 + (px & 15);
      *(u16x8*)(h + ((size_t)p * HWSZ + gpx) * CC + s * 8) = v;
    }
  }
}

// ---------------------------------------------------------------- conv2
// grid (64 tiles 16x16, 8 b), 512 thr, 2 blocks/CU. Full wt prefetch pipeline:
// slot1-h0 loads issued under slot0-h1 compute.
__global__ __launch_bounds__(512, 4) void conv2_kernel(const u16x8* __restrict__ h,
                                                       const u16x8* __restrict__ wp2,
                                                       const float* __restrict__ bg2p,
                                                       float* __restrict__ out) {
  __shared__ u16x8 xt[XCH];
  __shared__ u16x8 wt[WHALF];
  const int t = threadIdx.x, lane = t & 63, w = t >> 6;
  const int tile = blockIdx.x, b = blockIdx.y;
  const int ty0 = (tile >> 3) * 16, tx0 = (tile & 7) * 16;

  f32x4 acc[2][4];
#pragma unroll
  for (int i = 0; i < 2; ++i)
#pragma unroll
    for (int j = 0; j < 4; ++j) acc[i][j] = (f32x4){0.f, 0.f, 0.f, 0.f};

  const u16x8* ws0 = wp2 + (size_t)(2 * b) * WCHUNKS;
  const u16x8* ws1 = wp2 + (size_t)(2 * b + 1) * WCHUNKS;
  u16x8 pw[5];

  stage_xt2(h + (size_t)(2 * b) * HWSZ * 8, xt, ty0, tx0, t);
#pragma unroll
  for (int i = 0; i < 5; ++i) {
    const int idx = i * 512 + t;
    if (idx < WHALF) wt[idx] = ws0[idx];
  }
  __syncthreads();

  // slot0 half0 (prefetch s0h1)
#pragma unroll
  for (int i = 0; i < 5; ++i) {
    const int idx = i * 512 + t;
    if (idx < WHALF) pw[i] = ws0[WHALF + idx];
  }
  __builtin_amdgcn_s_setprio(1);
  half_body2(xt, wt, 0, lane, w, acc);
  __builtin_amdgcn_s_setprio(0);
  __syncthreads();
#pragma unroll
  for (int i = 0; i < 5; ++i) {
    const int idx = i * 512 + t;
    if (idx < WHALF) wt[idx] = pw[i];
  }
  __syncthreads();

  // slot0 half1 (prefetch s1h0)
#pragma unroll
  for (int i = 0; i < 5; ++i) {
    const int idx = i * 512 + t;
    if (idx < WHALF) pw[i] = ws1[idx];
  }
  __builtin_amdgcn_s_setprio(1);
  half_body2(xt, wt, 1, lane, w, acc);
  __builtin_amdgcn_s_setprio(0);
  __syncthreads();   // xt + wt readers done

  // restage xt for slot1; wt <- prefetched s1h0
  stage_xt2(h + (size_t)(2 * b + 1) * HWSZ * 8, xt, ty0, tx0, t);
#pragma unroll
  for (int i = 0; i < 5; ++i) {
    const int idx = i * 512 + t;
    if (idx < WHALF) wt[idx] = pw[i];
  }
  __syncthreads();

  // slot1 half0 (prefetch s1h1)
#pragma unroll
  for (int i = 0; i < 5; ++i) {
    const int idx = i * 512 + t;
    if (idx < WHALF) pw[i] = ws1[WHALF + idx];
  }
  __builtin_amdgcn_s_setprio(1);
  half_body2(xt, wt, 0, lane, w, acc);
  __builtin_amdgcn_s_setprio(0);
  __syncthreads();
#pragma unroll
  for (int i = 0; i < 5; ++i) {
    const int idx = i * 512 + t;
    if (idx < WHALF) wt[idx] = pw[i];
  }
  __syncthreads();

  // slot1 half1
  __builtin_amdgcn_s_setprio(1);
  half_body2(xt, wt, 1, lane, w, acc);
  __builtin_amdgcn_s_setprio(0);

  const int co_s = (lane >> 4) * 4;
  const int ln = lane & 15;
#pragma unroll
  for (int mf = 0; mf < 4; ++mf) {
    const float4 ba = *(const float4*)(bg2p + (2 * b) * CC + mf * 16 + co_s);
    const float4 bb = *(const float4*)(bg2p + (2 * b + 1) * CC + mf * 16 + co_s);
    const float bx = ba.x + bb.x;
    const float by = ba.y + bb.y;
    const float bz = ba.z + bb.z;
    const float bw = ba.w + bb.w;
#pragma unroll
    for (int nfr = 0; nfr < 2; ++nfr) {
      const int row = 2 * w + nfr;
      const int gpx = (ty0 + row) * WW + tx0 + ln;
      f32x4 v = acc[nfr][mf];
      float* ob = out + (size_t)(b * CC + mf * 16 + co_s) * HWSZ + gpx;
      ob[0 * HWSZ] = v.x + bx;
      ob[1 * HWSZ] = v.y + by;
      ob[2 * HWSZ] = v.z + bz;
      ob[3 * HWSZ] = v.w + bw;
    }
  }
}

// ---------------------------------------------------------------- launch
extern "C" void kernel_launch(void* const* d_in, const int* in_sizes, int n_in,
                              void* d_out, int out_size, void* d_ws, size_t ws_size,
                              hipStream_t stream) {
  const float* x   = (const float*)d_in[0];
  const float* txt = (const float*)d_in[1];
  const float* Wx  = (const float*)d_in[2];
  const float* Wt  = (const float*)d_in[3];
  const float* w1  = (const float*)d_in[4];
  const float* b1  = (const float*)d_in[5];
  const float* w2  = (const float*)d_in[6];
  const float* b2  = (const float*)d_in[7];
  float* out = (float*)d_out;

  char* ws = (char*)d_ws;
  float* pp   = (float*)ws;                                  // 131,072 B
  float* bg1  = (float*)(ws + 131072);                       // 4,096 B
  float* bg2p = (float*)(ws + 135168);                       // 4,096 B
  unsigned short* wp1 = (unsigned short*)(ws + 139264);      // 1,179,648 B
  unsigned short* wp2 = (unsigned short*)(ws + 1318912);     // 1,179,648 B
  unsigned short* xT  = (unsigned short*)(ws + 2498560);     // 16,777,216 B
  unsigned short* h   = (unsigned short*)(ws + 19275776);    // 33,554,432 B

  xtprep_kernel<<<dim3(64, 8), 256, 0, stream>>>(x, xT, pp);
  gwprep_kernel<<<dim3(16, 2, 4), 256, 0, stream>>>(pp, txt, Wx, Wt, w1, w2, b1, b2,
                                                    wp1, wp2, bg1, bg2p,
                                                    out + (out_size - 1));
  conv1_kernel<<<dim3(64, 8), 512, 0, stream>>>((const u16x8*)xT, (const u16x8*)wp1,
                                                bg1, (unsigned short*)h);
  conv2_kernel<<<dim3(64, 8), 512, 0, stream>>>((const u16x8*)h, (const u16x8*)wp2,
                                                bg2p, out);
}

// Round 9
// 95.896 us; speedup vs baseline: 1.2402x; 1.0519x over previous
//
#include <hip/hip_runtime.h>
#include <hip/hip_bf16.h>
#include <math.h>

typedef __attribute__((ext_vector_type(8))) short      bf16x8;
typedef __attribute__((ext_vector_type(8))) unsigned short u16x8;
typedef __attribute__((ext_vector_type(4))) unsigned short u16x4;
typedef __attribute__((ext_vector_type(4))) float       f32x4;

#define BB 8
#define CC 64
#define HH 128
#define WW 128
#define EE 16
#define DTXT 512
#define HWSZ 16384
#define WCHUNKS 4608      // per pair: 2half * 9k * 4slot * 64co 16B chunks
#define WHALF 2304        // one 32-ci half
#define HLO 18            // 16x16 tile + halo
#define HPX2 324
#define XCH (HPX2 * 8)    // 2592 16B chunks

static __device__ __forceinline__ unsigned short f2bf(float f) {
  unsigned u = __float_as_uint(f);
  unsigned r = (u + 0x7FFFu + ((u >> 16) & 1u)) >> 16;  // RNE
  return (unsigned short)r;
}
static __device__ __forceinline__ float bf2f(unsigned short s) {
  return __uint_as_float(((unsigned)s) << 16);
}

// exact-GELU via A&S 7.1.26 erf (|err| <= 1.5e-7, invisible at bf16)
static __device__ __forceinline__ float gelu_f(float x) {
  const float y = fabsf(x) * 0.70710678118654752f;
  const float t = __builtin_amdgcn_rcpf(1.f + 0.3275911f * y);
  float p = 1.061405429f;
  p = p * t - 1.453152027f;
  p = p * t + 1.421413741f;
  p = p * t - 0.284496736f;
  p = p * t + 0.254829592f;
  const float e = __expf(-y * y);
  const float erf_abs = 1.f - t * p * e;
  const float erf_s = copysignf(erf_abs, x);
  return 0.5f * x * (1.f + erf_s);
}

// ---------------------------------------------------------------- xtprep (+pool partials)
__global__ __launch_bounds__(256) void xtprep_kernel(const float* __restrict__ x,
                                                     unsigned short* __restrict__ xT,
                                                     float* __restrict__ pp) {
  __shared__ unsigned short lt[256 * 70];
  __shared__ float red[256];
  const int b = blockIdx.y, p0 = blockIdx.x * 256;
  const int t = threadIdx.x;
  const float* xb = x + (size_t)b * CC * HWSZ + p0;
#pragma unroll 8
  for (int ci = 0; ci < CC; ++ci)
    lt[t * 70 + ci] = f2bf(xb[(size_t)ci * HWSZ + t]);
  __syncthreads();
  unsigned short* dstb = xT + ((size_t)b * HWSZ + p0) * CC;
#pragma unroll
  for (int it = 0; it < 8; ++it) {
    const int j = it * 256 + t;
    const int px = j >> 3, s = j & 7;
    u16x8 v;
#pragma unroll
    for (int i = 0; i < 8; ++i) v[i] = lt[px * 70 + s * 8 + i];
    *(u16x8*)(dstb + (size_t)j * 8) = v;
  }
  const int ci = t & 63, q = t >> 6;
  float s = 0.f;
#pragma unroll 16
  for (int px = q * 64; px < q * 64 + 64; ++px) s += bf2f(lt[px * 70 + ci]);
  red[t] = s;
  __syncthreads();
  if (t < 64)
    pp[((size_t)b * 64 + blockIdx.x) * 64 + t] =
        red[t] + red[t + 64] + red[t + 128] + red[t + 192];
}

// ---------------------------------------------------------------- gwprep
// grid (16 pairs, 2 convs, 4 co-slices). Every block redundantly computes the
// gate, stages its contiguous 36.9KB w-slice in LDS (coalesced), then repacks.
__global__ __launch_bounds__(256) void gwprep_kernel(const float* __restrict__ pp,
                                                     const float* __restrict__ text,
                                                     const float* __restrict__ Wx,
                                                     const float* __restrict__ Wt,
                                                     const float* __restrict__ w1,
                                                     const float* __restrict__ w2,
                                                     const float* __restrict__ b1,
                                                     const float* __restrict__ b2,
                                                     unsigned short* __restrict__ wp1,
                                                     unsigned short* __restrict__ wp2,
                                                     float* __restrict__ bg1,
                                                     float* __restrict__ bg2p,
                                                     float* __restrict__ aux_out) {
  __shared__ float pl[BB][CC];
  __shared__ float tx[BB * DTXT];
  __shared__ float wtl[DTXT * EE];
  __shared__ float lw[16 * 577];      // 16 co x 576, pad to 577 (conflict-free)
  __shared__ float logits[BB][EE];
  __shared__ float gates[BB][EE];
  __shared__ float imp[EE];
  __shared__ int   s_eidx[16];
  __shared__ float s_gval[16];
  const int t = threadIdx.x;

#pragma unroll
  for (int i = 0; i < BB * DTXT / 4 / 256; ++i)
    ((float4*)tx)[i * 256 + t] = ((const float4*)text)[i * 256 + t];
#pragma unroll
  for (int i = 0; i < DTXT * EE / 4 / 256; ++i)
    ((float4*)wtl)[i * 256 + t] = ((const float4*)Wt)[i * 256 + t];

#pragma unroll
  for (int jj = 0; jj < 2; ++jj) {
    const int j = jj * 256 + t;
    const int b = j >> 6, ci = j & 63;
    float s = 0.f;
#pragma unroll 8
    for (int blk = 0; blk < 64; ++blk) s += pp[((size_t)b * 64 + blk) * 64 + ci];
    pl[b][ci] = s * (1.f / (float)HWSZ);
  }
  __syncthreads();

  if (t < BB * EE) {
    const int b = t >> 4, e = t & 15;
    float s = 0.f;
#pragma unroll 8
    for (int c = 0; c < CC; ++c) s += pl[b][c] * Wx[c * EE + e];
#pragma unroll 8
    for (int d = 0; d < DTXT; ++d) s += tx[b * DTXT + d] * wtl[d * EE + e];
    logits[b][e] = s;
    gates[b][e] = 0.f;
  }
  __syncthreads();
  if (t < BB) {
    const int b = t;
    float v0 = -1e30f; int i0 = 0;
    for (int e = 0; e < EE; ++e) {
      float v = logits[b][e];
      if (v > v0) { v0 = v; i0 = e; }
    }
    float v1 = -1e30f; int i1 = 0;
    for (int e = 0; e < EE; ++e) {
      if (e == i0) continue;
      float v = logits[b][e];
      if (v > v1) { v1 = v; i1 = e; }
    }
    const float ex = expf(v1 - v0);
    const float g0 = 1.f / (1.f + ex);
    const float g1 = ex / (1.f + ex);
    gates[b][i0] = g0;
    gates[b][i1] = g1;
    s_eidx[2 * b] = i0;      s_gval[2 * b] = g0;
    s_eidx[2 * b + 1] = i1;  s_gval[2 * b + 1] = g1;
  }
  __syncthreads();

  const int p = blockIdx.x;
  const int conv = blockIdx.y;
  const int z = blockIdx.z;
  const int e = s_eidx[p];
  const float g = conv ? s_gval[p] : 1.0f;

  if (z == 0 && t < CC) {
    if (conv == 0) bg1[p * CC + t] = b1[e * CC + t];
    else           bg2p[p * CC + t] = s_gval[p] * b2[e * CC + t];
  }
  if (p == 0 && conv == 0 && z == 0) {
    if (t < EE) {
      float s = 0.f;
      for (int b = 0; b < BB; ++b) s += gates[b][t];
      imp[t] = s;
    }
    __syncthreads();
    if (t == 0) {
      float m = 0.f;
      for (int ee = 0; ee < EE; ++ee) m += imp[ee];
      m *= (1.f / EE);
      float v = 0.f;
      for (int ee = 0; ee < EE; ++ee) { float d = imp[ee] - m; v += d * d; }
      v *= (1.f / EE);
      aux_out[0] = v / (m * m + 1e-10f);
    }
  }

  // stage this block's co-slice [z*16,(z+1)*16) of w[e]: 9216 floats, coalesced
  const float* wsl = (conv ? w2 : w1) + (size_t)e * CC * CC * 9 + (size_t)z * 16 * 576;
#pragma unroll
  for (int i = 0; i < 36; ++i) {
    const int f = i * 256 + t;          // f = co_l*576 + q
    const int co_l = f / 576, q = f - co_l * 576;
    lw[co_l * 577 + q] = wsl[f];
  }
  __syncthreads();

  // repack from LDS: 1152 chunks; c16 = rest*64 + z*16 + co_l
  unsigned short* dst = (conv ? wp2 : wp1) + (size_t)p * WCHUNKS * 8;
  for (int j = t; j < 1152; j += 256) {
    const int co_l = j & 15;
    const int rest = j >> 4;
    const int s = rest & 3;
    const int ck = rest >> 2;
    const int k = ck % 9, half = ck / 9;
    const int ci0 = half * 32 + s * 8;
    u16x8 v;
#pragma unroll
    for (int i = 0; i < 8; ++i)
      v[i] = f2bf(g * lw[co_l * 577 + (ci0 + i) * 9 + k]);
    const int c16 = rest * 64 + z * 16 + co_l;
    *(u16x8*)(dst + (size_t)c16 * 8) = v;
  }
}

// ------------------------------------------------- conv core helpers
static __device__ __forceinline__ void stage_xt2(const u16x8* __restrict__ src,
                                                 u16x8* xt, int ty0, int tx0, int t) {
#pragma unroll
  for (int i = 0; i < 6; ++i) {
    const int idx = i * 512 + t;
    if (idx < XCH) {
      const int ph = idx >> 3, s = idx & 7;
      const int yy = ph / HLO, xx = ph - yy * HLO;
      const int gy = ty0 - 1 + yy, gx = tx0 - 1 + xx;
      u16x8 v = (u16x8){0, 0, 0, 0, 0, 0, 0, 0};
      if ((unsigned)gy < (unsigned)HH && (unsigned)gx < (unsigned)WW)
        v = src[(gy * WW + gx) * 8 + s];
      xt[ph * 8 + (s ^ (ph & 7))] = v;
    }
  }
}

static __device__ __forceinline__ void half_body2(const u16x8* xt, const u16x8* wt,
                                                  int half, int lane, int w,
                                                  f32x4 acc[2][4]) {
  const int ks = lane >> 4, ln = lane & 15;
#pragma unroll
  for (int kk = 0; kk < 9; ++kk) {
    const int dy = kk / 3, dx = kk % 3;
    bf16x8 a[4];
#pragma unroll
    for (int mf = 0; mf < 4; ++mf)
      a[mf] = __builtin_bit_cast(bf16x8, wt[(kk * 4 + ks) * 64 + mf * 16 + ln]);
#pragma unroll
    for (int nfr = 0; nfr < 2; ++nfr) {
      const int row = 2 * w + nfr + dy;
      const int col = ln + dx;
      const int ph = row * HLO + col;
      const bf16x8 bfr = __builtin_bit_cast(bf16x8,
                xt[ph * 8 + ((half * 4 + ks) ^ (ph & 7))]);
#pragma unroll
      for (int mf = 0; mf < 4; ++mf)
        acc[nfr][mf] = __builtin_amdgcn_mfma_f32_16x16x32_bf16(a[mf], bfr,
                                                               acc[nfr][mf], 0, 0, 0);
    }
  }
}

// ---------------------------------------------------------------- conv1
// grid (64 tiles 16x16, 8 b), 512 thr, 2 blocks/CU. 4 wt stages pipelined
// (T14); setprio (T5); dual-scratch GELU epilogue (slot0->xt, slot1->wt).
__global__ __launch_bounds__(512, 4) void conv1_kernel(const u16x8* __restrict__ xT,
                                                       const u16x8* __restrict__ wp1,
                                                       const float* __restrict__ bg1,
                                                       unsigned short* __restrict__ h) {
  __shared__ u16x8 xt[XCH];     // 41472 B
  __shared__ u16x8 wt[WHALF];   // 36864 B -> 78336 B total
  const int t = threadIdx.x, lane = t & 63, w = t >> 6;
  const int tile = blockIdx.x, b = blockIdx.y;
  const int ty0 = (tile >> 3) * 16, tx0 = (tile & 7) * 16;

  f32x4 acc[2][2][4];   // [slot][nfr][mf]
#pragma unroll
  for (int s = 0; s < 2; ++s)
#pragma unroll
    for (int i = 0; i < 2; ++i)
#pragma unroll
      for (int j = 0; j < 4; ++j) acc[s][i][j] = (f32x4){0.f, 0.f, 0.f, 0.f};

  stage_xt2(xT + (size_t)b * HWSZ * 8, xt, ty0, tx0, t);
  {
    const u16x8* w0 = wp1 + (size_t)(2 * b) * WCHUNKS;
#pragma unroll
    for (int i = 0; i < 5; ++i) {
      const int idx = i * 512 + t;
      if (idx < WHALF) wt[idx] = w0[idx];
    }
  }
  __syncthreads();

  u16x8 pw[5];
#pragma unroll
  for (int st = 0; st < 4; ++st) {
    const int slot = st >> 1, half = st & 1;
    if (st < 3) {  // issue next stage's global loads before compute
      const u16x8* nw = wp1 + (size_t)(2 * b + ((st + 1) >> 1)) * WCHUNKS
                        + ((st + 1) & 1) * WHALF;
#pragma unroll
      for (int i = 0; i < 5; ++i) {
        const int idx = i * 512 + t;
        if (idx < WHALF) pw[i] = nw[idx];
      }
    }
    __builtin_amdgcn_s_setprio(1);
    half_body2(xt, wt, half, lane, w, acc[slot]);
    __builtin_amdgcn_s_setprio(0);
    __syncthreads();
    if (st < 3) {
#pragma unroll
      for (int i = 0; i < 5; ++i) {
        const int idx = i * 512 + t;
        if (idx < WHALF) wt[idx] = pw[i];
      }
      __syncthreads();
    }
  }

  // epilogue: both slots in one pass; slot0 -> xt scratch, slot1 -> wt scratch
  unsigned short* lt0 = (unsigned short*)xt;
  unsigned short* lt1 = (unsigned short*)wt;
  const int ks = lane >> 4, ln = lane & 15;
  const int co_s = ks * 4;
  const int so = co_s >> 3, off = co_s & 7;
#pragma unroll
  for (int slot = 0; slot < 2; ++slot) {
    unsigned short* lt = slot ? lt1 : lt0;
    const int p = 2 * b + slot;
#pragma unroll
    for (int mf = 0; mf < 4; ++mf) {
      const float4 bv = *(const float4*)(bg1 + p * CC + mf * 16 + co_s);
      const int s = mf * 2 + so;
#pragma unroll
      for (int nfr = 0; nfr < 2; ++nfr) {
        const int pxl = (2 * w + nfr) * 16 + ln;
        f32x4 v = acc[slot][nfr][mf];
        u16x4 pk = {f2bf(gelu_f(v.x + bv.x)), f2bf(gelu_f(v.y + bv.y)),
                    f2bf(gelu_f(v.z + bv.z)), f2bf(gelu_f(v.w + bv.w))};
        *(u16x4*)(lt + (pxl * 8 + (s ^ (pxl & 7))) * 8 + off) = pk;
      }
    }
  }
  __syncthreads();
  // coalesced copy-out: both slots, 4096 chunks
#pragma unroll
  for (int it = 0; it < 8; ++it) {
    const int j = it * 512 + t;
    const int slot = it >> 2;
    const int jj = j & 2047;
    const int px = jj >> 3, s = jj & 7;
    const u16x8 v = (slot ? (const u16x8*)wt : xt)[px * 8 + (s ^ (px & 7))];
    const int gpx = (ty0 + (px >> 4)) * WW + tx0 + (px & 15);
    *(u16x8*)(h + ((size_t)(2 * b + slot) * HWSZ + gpx) * CC + s * 8) = v;
  }
}

// ---------------------------------------------------------------- conv2
// grid (64 tiles 16x16, 8 b), 512 thr, 2 blocks/CU. Full wt prefetch pipeline.
__global__ __launch_bounds__(512, 4) void conv2_kernel(const u16x8* __restrict__ h,
                                                       const u16x8* __restrict__ wp2,
                                                       const float* __restrict__ bg2p,
                                                       float* __restrict__ out) {
  __shared__ u16x8 xt[XCH];
  __shared__ u16x8 wt[WHALF];
  const int t = threadIdx.x, lane = t & 63, w = t >> 6;
  const int tile = blockIdx.x, b = blockIdx.y;
  const int ty0 = (tile >> 3) * 16, tx0 = (tile & 7) * 16;

  f32x4 acc[2][4];
#pragma unroll
  for (int i = 0; i < 2; ++i)
#pragma unroll
    for (int j = 0; j < 4; ++j) acc[i][j] = (f32x4){0.f, 0.f, 0.f, 0.f};

  const u16x8* ws0 = wp2 + (size_t)(2 * b) * WCHUNKS;
  const u16x8* ws1 = wp2 + (size_t)(2 * b + 1) * WCHUNKS;
  u16x8 pw[5];

  stage_xt2(h + (size_t)(2 * b) * HWSZ * 8, xt, ty0, tx0, t);
#pragma unroll
  for (int i = 0; i < 5; ++i) {
    const int idx = i * 512 + t;
    if (idx < WHALF) wt[idx] = ws0[idx];
  }
  __syncthreads();

#pragma unroll
  for (int i = 0; i < 5; ++i) {
    const int idx = i * 512 + t;
    if (idx < WHALF) pw[i] = ws0[WHALF + idx];
  }
  __builtin_amdgcn_s_setprio(1);
  half_body2(xt, wt, 0, lane, w, acc);
  __builtin_amdgcn_s_setprio(0);
  __syncthreads();
#pragma unroll
  for (int i = 0; i < 5; ++i) {
    const int idx = i * 512 + t;
    if (idx < WHALF) wt[idx] = pw[i];
  }
  __syncthreads();

#pragma unroll
  for (int i = 0; i < 5; ++i) {
    const int idx = i * 512 + t;
    if (idx < WHALF) pw[i] = ws1[idx];
  }
  __builtin_amdgcn_s_setprio(1);
  half_body2(xt, wt, 1, lane, w, acc);
  __builtin_amdgcn_s_setprio(0);
  __syncthreads();

  stage_xt2(h + (size_t)(2 * b + 1) * HWSZ * 8, xt, ty0, tx0, t);
#pragma unroll
  for (int i = 0; i < 5; ++i) {
    const int idx = i * 512 + t;
    if (idx < WHALF) wt[idx] = pw[i];
  }
  __syncthreads();

#pragma unroll
  for (int i = 0; i < 5; ++i) {
    const int idx = i * 512 + t;
    if (idx < WHALF) pw[i] = ws1[WHALF + idx];
  }
  __builtin_amdgcn_s_setprio(1);
  half_body2(xt, wt, 0, lane, w, acc);
  __builtin_amdgcn_s_setprio(0);
  __syncthreads();
#pragma unroll
  for (int i = 0; i < 5; ++i) {
    const int idx = i * 512 + t;
    if (idx < WHALF) wt[idx] = pw[i];
  }
  __syncthreads();

  __builtin_amdgcn_s_setprio(1);
  half_body2(xt, wt, 1, lane, w, acc);
  __builtin_amdgcn_s_setprio(0);

  const int co_s = (lane >> 4) * 4;
  const int ln = lane & 15;
#pragma unroll
  for (int mf = 0; mf < 4; ++mf) {
    const float4 ba = *(const float4*)(bg2p + (2 * b) * CC + mf * 16 + co_s);
    const float4 bb = *(const float4*)(bg2p + (2 * b + 1) * CC + mf * 16 + co_s);
    const float bx = ba.x + bb.x;
    const float by = ba.y + bb.y;
    const float bz = ba.z + bb.z;
    const float bw = ba.w + bb.w;
#pragma unroll
    for (int nfr = 0; nfr < 2; ++nfr) {
      const int row = 2 * w + nfr;
      const int gpx = (ty0 + row) * WW + tx0 + ln;
      f32x4 v = acc[nfr][mf];
      float* ob = out + (size_t)(b * CC + mf * 16 + co_s) * HWSZ + gpx;
      ob[0 * HWSZ] = v.x + bx;
      ob[1 * HWSZ] = v.y + by;
      ob[2 * HWSZ] = v.z + bz;
      ob[3 * HWSZ] = v.w + bw;
    }
  }
}

// ---------------------------------------------------------------- launch
extern "C" void kernel_launch(void* const* d_in, const int* in_sizes, int n_in,
                              void* d_out, int out_size, void* d_ws, size_t ws_size,
                              hipStream_t stream) {
  const float* x   = (const float*)d_in[0];
  const float* txt = (const float*)d_in[1];
  const float* Wx  = (const float*)d_in[2];
  const float* Wt  = (const float*)d_in[3];
  const float* w1  = (const float*)d_in[4];
  const float* b1  = (const float*)d_in[5];
  const float* w2  = (const float*)d_in[6];
  const float* b2  = (const float*)d_in[7];
  float* out = (float*)d_out;

  char* ws = (char*)d_ws;
  float* pp   = (float*)ws;                                  // 131,072 B
  float* bg1  = (float*)(ws + 131072);                       // 4,096 B
  float* bg2p = (float*)(ws + 135168);                       // 4,096 B
  unsigned short* wp1 = (unsigned short*)(ws + 139264);      // 1,179,648 B
  unsigned short* wp2 = (unsigned short*)(ws + 1318912);     // 1,179,648 B
  unsigned short* xT  = (unsigned short*)(ws + 2498560);     // 16,777,216 B
  unsigned short* h   = (unsigned short*)(ws + 19275776);    // 33,554,432 B

  xtprep_kernel<<<dim3(64, 8), 256, 0, stream>>>(x, xT, pp);
  gwprep_kernel<<<dim3(16, 2, 4), 256, 0, stream>>>(pp, txt, Wx, Wt, w1, w2, b1, b2,
                                                    wp1, wp2, bg1, bg2p,
                                                    out + (out_size - 1));
  conv1_kernel<<<dim3(64, 8), 512, 0, stream>>>((const u16x8*)xT, (const u16x8*)wp1,
                                                bg1, (unsigned short*)h);
  conv2_kernel<<<dim3(64, 8), 512, 0, stream>>>((const u16x8*)h, (const u16x8*)wp2,
                                                bg2p, out);
}